// Round 3
// baseline (365.245 us; speedup 1.0000x reference)
//
#include <hip/hip_runtime.h>
#include <math.h>

// ---------------------------------------------------------------------------
// gram = x^T x (N=4M, D=10, fp64-accurate reduction) -> fp32 -> LAPACK-
// faithful fp32 ssyevd path (ssytd2 'L' + ssteqr, LAPACK>=3.10 slartg) -> MLP.
// Round 8 (gram tail): kill the atomic reduction.
//  * Rounds 5/6/7 rebuilt the load loop three different ways and the kernel
//    stayed at 88-94 us -> the shared bottleneck was the TAIL: 1024 blocks x
//    55 fp64 atomicAdds onto 28 cache lines (4 replicas); device-scope
//    same-line RMWs from 8 XCDs serialize (~2048 ops/line) ~ 40-90 us.
//  * Now each block stores its 55 fp64 partials to a PRIVATE slot, k-major
//    g[k*GRID2 + b] (no atomics, no contention, stores to distinct bytes).
//    zero_ws_kernel is gone (every block writes unconditionally).
//  * eig kernel prologue: per component k, 64 lanes read the 1024 partials
//    coalesced (16 loads/lane) + shuffle-tree reduce -> LDS -> uniform use.
//    fp64 reassociation is safe: atomic order was already nondeterministic
//    and the fp32 rounding of gram entries has ~1e6x margin vs fp64 noise.
//  * gram load loop itself is round 7's (wave-private LDS, barrier-free).
// ---------------------------------------------------------------------------

#define BLK2 256
#define GRID2 1024
#define WTILE_F4 320                 // per-wave tile: 5 steps x 64 lanes
#define TILE_F4 (BLK2 * 5)           // 1280 float4 = 512 rows per block tile

__global__ __launch_bounds__(BLK2) void gram_kernel(const float4* __restrict__ x4,
                                                    double* __restrict__ g,
                                                    int nf4) {
  __shared__ float4 lds[4][WTILE_F4];  // 4 waves x 5KB, wave-private slices
  float acc[55];
#pragma unroll
  for (int k = 0; k < 55; k++) acc[k] = 0.0f;

  const int tid = threadIdx.x;
  const int lane = tid & 63;
  const int wv = tid >> 6;
  float4* const wl = lds[wv];
  const int ntiles = (nf4 + TILE_F4 - 1) / TILE_F4;
  const float4 zz = make_float4(0.f, 0.f, 0.f, 0.f);

  int t = (int)blockIdx.x;
  bool active = (t < ntiles);

  // stage tile t into this wave's LDS slice (coalesced, guarded)
  if (active) {
    const int wb = t * TILE_F4 + wv * WTILE_F4;
#pragma unroll
    for (int s = 0; s < 5; s++) {
      int i = wb + s * 64 + lane;
      wl[s * 64 + lane] = (i < nf4) ? x4[i] : zz;
    }
  }

  while (active) {
    // issue next tile's coalesced loads into registers (overlaps compute)
    const int tn = t + GRID2;
    const bool an = (tn < ntiles);
    float4 n0 = zz, n1 = zz, n2 = zz, n3 = zz, n4 = zz;
    if (an) {
      const int wb = tn * TILE_F4 + wv * WTILE_F4;
      int i0 = wb + 0 * 64 + lane;
      int i1 = wb + 1 * 64 + lane;
      int i2 = wb + 2 * 64 + lane;
      int i3 = wb + 3 * 64 + lane;
      int i4 = wb + 4 * 64 + lane;
      n0 = (i0 < nf4) ? x4[i0] : zz;
      n1 = (i1 < nf4) ? x4[i1] : zz;
      n2 = (i2 < nf4) ? x4[i2] : zz;
      n3 = (i3 < nf4) ? x4[i3] : zz;
      n4 = (i4 < nf4) ? x4[i4] : zz;
    }

    // transposed read of current tile: thread gets its 2 contiguous rows
    float4 q0 = wl[lane * 5 + 0];
    float4 q1 = wl[lane * 5 + 1];
    float4 q2 = wl[lane * 5 + 2];
    float4 q3 = wl[lane * 5 + 3];
    float4 q4 = wl[lane * 5 + 4];
    float v[20] = {q0.x, q0.y, q0.z, q0.w, q1.x, q1.y, q1.z, q1.w,
                   q2.x, q2.y, q2.z, q2.w, q3.x, q3.y, q3.z, q3.w,
                   q4.x, q4.y, q4.z, q4.w};
    int k = 0;
#pragma unroll
    for (int i = 0; i < 10; i++) {
#pragma unroll
      for (int j = 0; j <= i; j++) {
        acc[k] += v[i] * v[j] + v[10 + i] * v[10 + j];
        k++;
      }
    }

    // write next tile into LDS (after this wave's reads; DS ops are in-order
    // within a wave, so no barrier is needed)
    if (an) {
      wl[0 * 64 + lane] = n0;
      wl[1 * 64 + lane] = n1;
      wl[2 * 64 + lane] = n2;
      wl[3 * 64 + lane] = n3;
      wl[4 * 64 + lane] = n4;
    }
    t = tn;
    active = an;
  }

  __shared__ double sred[4][55];
#pragma unroll
  for (int k = 0; k < 55; k++) {
    double d = (double)acc[k];
#pragma unroll
    for (int off = 32; off > 0; off >>= 1) d += __shfl_down(d, off, 64);
    if (lane == 0) sred[wv][k] = d;
  }
  __syncthreads();
  // block-private partial store, k-major: g[k*GRID2 + b]; no atomics.
  if (threadIdx.x < 55) {
    double s = sred[0][threadIdx.x] + sred[1][threadIdx.x] +
               sred[2][threadIdx.x] + sred[3][threadIdx.x];
    g[threadIdx.x * GRID2 + blockIdx.x] = s;
  }
}

// ------------------------- LAPACK helpers (fp32) ---------------------------

__device__ __forceinline__ float sf_sign(float a, float b) {
  return (b >= 0.0f) ? fabsf(a) : -fabsf(a);
}

__device__ __forceinline__ float slapy2(float x, float y) {
  float xa = fabsf(x), ya = fabsf(y);
  float w = fmaxf(xa, ya), z = fminf(xa, ya);
  if (z == 0.0f) return w;
  float q = z / w;
  return w * sqrtf(1.0f + q * q);
}

// LAPACK >= 3.10 slartg: c = |f|/d >= 0, r = sign(f)*d, s = g/r
__device__ __forceinline__ void slartg(float f, float g, float* c, float* s, float* r) {
  if (g == 0.0f) {
    *c = 1.0f; *s = 0.0f; *r = f;
  } else if (f == 0.0f) {
    *c = 0.0f; *s = sf_sign(1.0f, g); *r = fabsf(g);
  } else {
    float d = sqrtf(f * f + g * g);
    *c = fabsf(f) / d;
    float rr = sf_sign(d, f);
    *s = g / rr;
    *r = rr;
  }
}

__device__ __forceinline__ void slaev2(float a, float b, float c,
                                       float* rt1, float* rt2, float* cs1, float* sn1) {
  float sm = a + c;
  float df = a - c;
  float adf = fabsf(df);
  float tb = b + b;
  float ab = fabsf(tb);
  float acmx, acmn;
  if (fabsf(a) > fabsf(c)) { acmx = a; acmn = c; } else { acmx = c; acmn = a; }
  float rt;
  if (adf > ab)      { float t = ab / adf; rt = adf * sqrtf(1.0f + t * t); }
  else if (adf < ab) { float t = adf / ab; rt = ab * sqrtf(1.0f + t * t); }
  else               { rt = ab * sqrtf(2.0f); }
  int sgn1;
  if (sm < 0.0f) {
    *rt1 = 0.5f * (sm - rt); sgn1 = -1;
    *rt2 = (acmx / *rt1) * acmn - (b / *rt1) * b;
  } else if (sm > 0.0f) {
    *rt1 = 0.5f * (sm + rt); sgn1 = 1;
    *rt2 = (acmx / *rt1) * acmn - (b / *rt1) * b;
  } else {
    *rt1 = 0.5f * rt; *rt2 = -0.5f * rt; sgn1 = 1;
  }
  int sgn2;
  float cs;
  if (df >= 0.0f) { cs = df + rt; sgn2 = 1; } else { cs = df - rt; sgn2 = -1; }
  float acs = fabsf(cs);
  if (acs > ab) {
    float ct = -tb / cs;
    *sn1 = 1.0f / sqrtf(1.0f + ct * ct);
    *cs1 = ct * (*sn1);
  } else {
    if (ab == 0.0f) { *cs1 = 1.0f; *sn1 = 0.0f; }
    else {
      float tn = -cs / tb;
      *cs1 = 1.0f / sqrtf(1.0f + tn * tn);
      *sn1 = tn * (*cs1);
    }
  }
  if (sgn1 == sgn2) { float tn = *cs1; *cs1 = -(*sn1); *sn1 = tn; }
}

// 10-way register select / masked write (runtime idx0, 0-based); branch-free.
// Used ONLY outside hot loops (once-per-sweep spots, 2x2 blocks, sort).
__device__ __forceinline__ float sel10(const float* a, int idx0) {
  float v = 0.0f;
#pragma unroll
  for (int k = 0; k < 10; k++) v = (k == idx0) ? a[k] : v;
  return v;
}
__device__ __forceinline__ void put10(float* a, int idx0, float v) {
#pragma unroll
  for (int k = 0; k < 10; k++) a[k] = (k == idx0) ? v : a[k];
}

// static 1-based access macros (indices must be compile-time constants)
#define A_(r, c) Am[((r)-1) * 10 + ((c)-1)]
#define Z_(r, c) Zm[((r)-1) * 10 + ((c)-1)]
#define D_(i) dv[(i)-1]
#define E_(i) ev[(i)-1]
#define TAUV(i) tauv[(i)-1]
#define WV(i) wvv[(i)-1]

__global__ __launch_bounds__(64, 1) void eig_mlp_kernel(
    const double* __restrict__ g,
    const float* __restrict__ W1,
    const float* __restrict__ b1,
    const float* __restrict__ W2,
    const float* __restrict__ b2,
    float* __restrict__ out) {
  if (blockIdx.x != 0) return;
  const int lane = threadIdx.x;
  const int n = 10;
  float Am[100], Zm[100];
  float dv[10], ev[10], tauv[10], wvv[10], csv[10], snv[10];

  // -------- reduce 1024 block partials per component (coalesced + shfl) ----
  __shared__ double gsum[55];
  for (int k = 0; k < 55; k++) {
    double s = 0.0;
#pragma unroll
    for (int j = 0; j < GRID2 / 64; j++) s += g[k * GRID2 + j * 64 + lane];
#pragma unroll
    for (int off = 32; off > 0; off >>= 1) s += __shfl_down(s, off, 64);
    if (lane == 0) gsum[k] = s;
  }
  __syncthreads();

  // load gram, round to fp32 — uniform on all lanes
  {
    int k = 0;
#pragma unroll
    for (int i = 0; i < 10; i++)
#pragma unroll
      for (int j = 0; j <= i; j++) {
        float f = (float)gsum[k];
        Am[i * 10 + j] = f;
        Am[j * 10 + i] = f;
        k++;
      }
  }

  // -------- ssytd2 (UPLO='L'), static, register-resident, uniform --------
#pragma unroll
  for (int i = 1; i <= n - 1; i++) {
    const int nmi = n - i;
    float alpha = A_(i + 1, i);
    float taui = 0.0f;
    if (nmi > 1) {
      float ss = 0.0f;
#pragma unroll
      for (int r = i + 2; r <= n; r++) { float t = A_(r, i); ss += t * t; }
      float xnorm = sqrtf(ss);
      if (xnorm != 0.0f) {
        float beta = -sf_sign(slapy2(alpha, xnorm), alpha);
        taui = (beta - alpha) / beta;
        float sc = 1.0f / (alpha - beta);
#pragma unroll
        for (int r = i + 2; r <= n; r++) A_(r, i) *= sc;
        alpha = beta;
      }
    }
    E_(i) = alpha;
    A_(i + 1, i) = alpha;
    if (taui != 0.0f) {
      A_(i + 1, i) = 1.0f;
#pragma unroll
      for (int r = i + 1; r <= n; r++) {
        float s = 0.0f;
#pragma unroll
        for (int c = i + 1; c <= n; c++) {
          float arc = (r >= c) ? A_(r, c) : A_(c, r);
          s += arc * A_(c, i);
        }
        WV(r) = taui * s;
      }
      float dot = 0.0f;
#pragma unroll
      for (int r = i + 1; r <= n; r++) dot += WV(r) * A_(r, i);
      float al2 = -0.5f * taui * dot;
#pragma unroll
      for (int r = i + 1; r <= n; r++) WV(r) += al2 * A_(r, i);
#pragma unroll
      for (int c = i + 1; c <= n; c++)
#pragma unroll
        for (int r = c; r <= n; r++)
          A_(r, c) -= A_(r, i) * WV(c) + WV(r) * A_(c, i);
      A_(i + 1, i) = E_(i);
    }
    D_(i) = A_(i, i);
    TAUV(i) = taui;
  }
  D_(n) = A_(n, n);

  // -------- form Q0 = H(1)...H(n-1), static, uniform --------
#pragma unroll
  for (int r = 1; r <= n; r++)
#pragma unroll
    for (int c = 1; c <= n; c++) Z_(r, c) = (r == c) ? 1.0f : 0.0f;
#pragma unroll
  for (int i = n - 1; i >= 1; i--) {
    float taui = TAUV(i);
    if (taui != 0.0f) {
#pragma unroll
      for (int c = 1; c <= n; c++) {
        float t = Z_(i + 1, c);
#pragma unroll
        for (int r = i + 2; r <= n; r++) t += A_(r, i) * Z_(r, c);
        t *= taui;
        Z_(i + 1, c) -= t;
#pragma unroll
        for (int r = i + 2; r <= n; r++) Z_(r, c) -= A_(r, i) * t;
      }
    }
  }

  // -------- distribute Z rows: lane r holds row r as z[0..9] --------
  const int r_own = (lane < 10) ? lane : 0;
  float z[10];
#pragma unroll
  for (int k = 0; k < 10; k++) {
    float v = Zm[0 * 10 + k];
#pragma unroll
    for (int rr = 1; rr < 10; rr++) v = (r_own == rr) ? Zm[rr * 10 + k] : v;
    z[k] = v;
  }

  // -------- ssteqr ('V'); sweeps statically unrolled w/ range guards ------
  const float eps = 5.9604644775390625e-08f;      // 2^-24
  const float eps2 = eps * eps;
  const float safmin = 1.17549435082228751e-38f;  // 2^-126
  const int nmaxit = n * 30;
  int jtot = 0;
  int l1 = 1;
  int guard = 0;

  while (l1 <= n && guard++ < 2000) {
    if (l1 > 1) put10(ev, l1 - 2, 0.0f);  // E_(l1-1) = 0
    int m = n;
    {
      bool found = false;
#pragma unroll
      for (int k = 1; k <= n - 1; k++) {
        if (!found && k >= l1) {
          float tst = fabsf(ev[k - 1]);
          if (tst == 0.0f) {
            m = k; found = true;
          } else if (tst <= (sqrtf(fabsf(dv[k - 1])) * sqrtf(fabsf(dv[k]))) * eps) {
            ev[k - 1] = 0.0f;
            m = k; found = true;
          }
        }
      }
    }
    int l = l1, lsv = l, lend = m, lendsv = m;
    l1 = m + 1;
    if (lend == l) continue;
    if (fabsf(sel10(dv, lend - 1)) < fabsf(sel10(dv, l - 1))) { lend = lsv; l = lendsv; }

    if (lend > l) {
      // ---------------- QL iteration ----------------
      for (;;) {
        if (guard++ > 4000) break;
        int m2 = lend;
        if (l != lend) {
          bool fnd = false;
#pragma unroll
          for (int k = 1; k <= n - 1; k++) {
            if (!fnd && k >= l && k <= lend - 1) {
              float e = ev[k - 1];
              if (e * e <= (eps2 * fabsf(dv[k - 1])) * fabsf(dv[k]) + safmin) {
                m2 = k; fnd = true;
              }
            }
          }
        }
        if (m2 < lend) put10(ev, m2 - 1, 0.0f);
        float p = sel10(dv, l - 1);
        if (m2 == l) {  // eigenvalue found
          put10(dv, l - 1, p);
          l = l + 1;
          if (l <= lend) continue;
          break;
        }
        if (m2 == l + 1) {  // 2x2 block; 0-based cols (l, l-1)
          float rt1, rt2, c2, s2;
          slaev2(sel10(dv, l - 1), sel10(ev, l - 1), sel10(dv, l), &rt1, &rt2, &c2, &s2);
          float a = sel10(z, l);
          float b = sel10(z, l - 1);
          put10(z, l, c2 * a - s2 * b);
          put10(z, l - 1, s2 * a + c2 * b);
          put10(dv, l - 1, rt1);
          put10(dv, l, rt2);
          put10(ev, l - 1, 0.0f);
          l = l + 2;
          if (l <= lend) continue;
          break;
        }
        if (jtot == nmaxit) break;
        jtot++;
        float El = sel10(ev, l - 1);
        float gg = (sel10(dv, l) - p) / (2.0f * El);
        float rr = slapy2(gg, 1.0f);
        gg = sel10(dv, m2 - 1) - p + (El / (gg + sf_sign(rr, gg)));
        float s = 1.0f, c = 1.0f;
        p = 0.0f;
        // rotation recurrence, static descending unroll w/ scalar guards
#pragma unroll
        for (int i = n - 1; i >= 1; i--) {
          if (i <= m2 - 1 && i >= l) {
            float e = ev[i - 1];
            float f = s * e, b = c * e;
            slartg(gg, f, &c, &s, &rr);
            if (i != m2 - 1) ev[i] = rr;  // E_(i+1), static
            gg = dv[i] - p;               // D_(i+1)
            rr = (dv[i - 1] - gg) * s + 2.0f * c * b;
            p = s * rr;
            dv[i] = gg + p;
            gg = c * rr - b;
            csv[i - 1] = c;
            snv[i - 1] = -s;
          }
        }
        // apply rotations (slasr 'B'): descending j, 0-based cols (j, j-1)
        {
          float a = sel10(z, m2 - 1);  // carried updated value of col j
#pragma unroll
          for (int j = n - 1; j >= 1; j--) {
            if (j <= m2 - 1 && j >= l) {
              float cj = csv[j - 1], sj = snv[j - 1];  // static
              float b = z[j - 1];                      // untouched original
              z[j] = cj * a - sj * b;                  // final col j
              a = sj * a + cj * b;                     // new col j-1, carried
            }
          }
          put10(z, l - 1, a);
        }
        put10(dv, l - 1, sel10(dv, l - 1) - p);
        put10(ev, l - 1, gg);
      }
    } else {
      // ---------------- QR iteration ----------------
      for (;;) {
        if (guard++ > 4000) break;
        int m2 = lend;
        if (l != lend) {
          bool fnd = false;
#pragma unroll
          for (int k = n; k >= 2; k--) {
            if (!fnd && k <= l && k >= lend + 1) {
              float e = ev[k - 2];
              if (e * e <= (eps2 * fabsf(dv[k - 1])) * fabsf(dv[k - 2]) + safmin) {
                m2 = k; fnd = true;
              }
            }
          }
        }
        if (m2 > lend) put10(ev, m2 - 2, 0.0f);  // E_(m2-1) = 0
        float p = sel10(dv, l - 1);
        if (m2 == l) {  // eigenvalue found
          put10(dv, l - 1, p);
          l = l - 1;
          if (l >= lend) continue;
          break;
        }
        if (m2 == l - 1) {  // 2x2 block; 0-based cols (l-1, l-2)
          float rt1, rt2, c2, s2;
          slaev2(sel10(dv, l - 2), sel10(ev, l - 2), sel10(dv, l - 1), &rt1, &rt2, &c2, &s2);
          float a = sel10(z, l - 1);
          float b = sel10(z, l - 2);
          put10(z, l - 1, c2 * a - s2 * b);
          put10(z, l - 2, s2 * a + c2 * b);
          put10(dv, l - 2, rt1);
          put10(dv, l - 1, rt2);
          put10(ev, l - 2, 0.0f);
          l = l - 2;
          if (l >= lend) continue;
          break;
        }
        if (jtot == nmaxit) break;
        jtot++;
        float El1 = sel10(ev, l - 2);  // E_(l-1)
        float gg = (sel10(dv, l - 2) - p) / (2.0f * El1);
        float rr = slapy2(gg, 1.0f);
        gg = sel10(dv, m2 - 1) - p + (El1 / (gg + sf_sign(rr, gg)));
        float s = 1.0f, c = 1.0f;
        p = 0.0f;
        // rotation recurrence, static ascending unroll w/ scalar guards
#pragma unroll
        for (int i = 1; i <= n - 1; i++) {
          if (i >= m2 && i <= l - 1) {
            float e = ev[i - 1];
            float f = s * e, b = c * e;
            slartg(gg, f, &c, &s, &rr);
            if (i >= 2) {
              if (i != m2) ev[i - 2] = rr;  // E_(i-1), static
            }
            gg = dv[i - 1] - p;  // D_(i)
            rr = (dv[i] - gg) * s + 2.0f * c * b;
            p = s * rr;
            dv[i - 1] = gg + p;
            gg = c * rr - b;
            csv[i - 1] = c;
            snv[i - 1] = s;
          }
        }
        // apply rotations (slasr 'F'): ascending j, 0-based cols (j, j-1)
        {
          float carry = sel10(z, m2 - 1);  // current value of col j-1
#pragma unroll
          for (int j = 1; j <= n - 1; j++) {
            if (j >= m2 && j <= l - 1) {
              float cj = csv[j - 1], sj = snv[j - 1];  // static
              float t = z[j];                          // untouched original
              z[j - 1] = sj * t + cj * carry;          // final col j-1
              carry = cj * t - sj * carry;             // new col j, carried
            }
          }
          put10(z, l - 1, carry);
        }
        put10(dv, l - 1, sel10(dv, l - 1) - p);
        put10(ev, l - 2, gg);  // E_(l-1)
      }
    }
  }

  // -------- selection sort ascending (as in ssteqr), uniform --------
  for (int ii = 2; ii <= n; ii++) {
    int i = ii - 1;
    int k = i;
    float p = sel10(dv, i - 1);
    for (int j = ii; j <= n; j++) {
      float dj = sel10(dv, j - 1);
      if (dj < p) { k = j; p = dj; }
    }
    if (k != i) {
      float di = sel10(dv, i - 1);
      put10(dv, k - 1, di);
      put10(dv, i - 1, p);
      float a = sel10(z, i - 1), b = sel10(z, k - 1);
      put10(z, i - 1, b);
      put10(z, k - 1, a);
    }
  }

  // -------- MLP per lane (lane r computes output row r) --------
  if (lane < 10) {
    double o = (double)b2[0];
#pragma unroll
    for (int h = 0; h < 16; h++) {
      double sgm = (double)b1[h];
#pragma unroll
      for (int k = 0; k < 10; k++) sgm += (double)z[k] * (double)W1[h * 10 + k];
      if (sgm > 0.0) o += sgm * (double)W2[h];
    }
    double sig = 1.0 / (1.0 + exp(-o));
    out[lane] = (float)(0.5 * (sig + 1.0));
  }
}

extern "C" void kernel_launch(void* const* d_in, const int* in_sizes, int n_in,
                              void* d_out, int out_size, void* d_ws, size_t ws_size,
                              hipStream_t stream) {
  const float* x  = (const float*)d_in[0];
  const float* W1 = (const float*)d_in[1];
  const float* b1 = (const float*)d_in[2];
  const float* W2 = (const float*)d_in[3];
  const float* b2 = (const float*)d_in[4];
  double* g = (double*)d_ws;
  float* out = (float*)d_out;

  int nf4 = in_sizes[0] / 4;  // 10M float4

  gram_kernel<<<GRID2, BLK2, 0, stream>>>((const float4*)x, g, nf4);
  eig_mlp_kernel<<<1, 64, 0, stream>>>(g, W1, b1, W2, b2, out);
}

// Round 4
// 362.764 us; speedup vs baseline: 1.0068x; 1.0068x over previous
//
#include <hip/hip_runtime.h>
#include <math.h>

// ---------------------------------------------------------------------------
// gram = x^T x (N=4M, D=10, fp64-accurate reduction) -> fp32 -> LAPACK-
// faithful fp32 ssyevd path (ssytd2 'L' + ssteqr, LAPACK>=3.10 slartg) -> MLP.
// Round 9 (reduction topology): 64-replica atomic tail + cheap eig prologue.
//  * Round 5: 4 replicas -> 256 colliding blocks/address on 28 lines ->
//    ~2048 serialized RMWs/line ~ 40+ us atomic tail (gram stuck at 94 us).
//  * Round 8: private per-block partials (no atomics) fixed gram (~35 us)
//    but the eig-side reduction (55 non-unrolled iterations x 16 far-L2
//    loads from ONE CU) cost ~60 us -> eig ballooned to 115 us.
//  * Round 9: gram atomicAdds into 64 replicas g[k*64 + (blk&63)]: 16
//    RMWs/address over 440 lines -> ~2-3 us tail. eig reduces 64 replicas
//    per component with ONE coalesced 512B load + 6-step shuffle tree,
//    fully unrolled -> ~2-3 us prologue. fp64 reassociation already proven
//    safe (absmax 0.0 under two different summation orders).
//  * gram load loop unchanged (round 7 wave-private LDS, barrier-free).
//    eig numerics byte-identical to rounds 2-8.
// ---------------------------------------------------------------------------

#define BLK2 256
#define GRID2 1024
#define NREP 64                      // partial-sum replicas (contention 16x)
#define WTILE_F4 320                 // per-wave tile: 5 steps x 64 lanes
#define TILE_F4 (BLK2 * 5)           // 1280 float4 = 512 rows per block tile

__global__ void zero_ws_kernel(double* __restrict__ g) {
  int t = blockIdx.x * 256 + threadIdx.x;
  if (t < 55 * NREP) g[t] = 0.0;
}

__global__ __launch_bounds__(BLK2) void gram_kernel(const float4* __restrict__ x4,
                                                    double* __restrict__ g,
                                                    int nf4) {
  __shared__ float4 lds[4][WTILE_F4];  // 4 waves x 5KB, wave-private slices
  float acc[55];
#pragma unroll
  for (int k = 0; k < 55; k++) acc[k] = 0.0f;

  const int tid = threadIdx.x;
  const int lane = tid & 63;
  const int wv = tid >> 6;
  float4* const wl = lds[wv];
  const int ntiles = (nf4 + TILE_F4 - 1) / TILE_F4;
  const float4 zz = make_float4(0.f, 0.f, 0.f, 0.f);

  int t = (int)blockIdx.x;
  bool active = (t < ntiles);

  // stage tile t into this wave's LDS slice (coalesced, guarded)
  if (active) {
    const int wb = t * TILE_F4 + wv * WTILE_F4;
#pragma unroll
    for (int s = 0; s < 5; s++) {
      int i = wb + s * 64 + lane;
      wl[s * 64 + lane] = (i < nf4) ? x4[i] : zz;
    }
  }

  while (active) {
    // issue next tile's coalesced loads into registers (overlaps compute)
    const int tn = t + GRID2;
    const bool an = (tn < ntiles);
    float4 n0 = zz, n1 = zz, n2 = zz, n3 = zz, n4 = zz;
    if (an) {
      const int wb = tn * TILE_F4 + wv * WTILE_F4;
      int i0 = wb + 0 * 64 + lane;
      int i1 = wb + 1 * 64 + lane;
      int i2 = wb + 2 * 64 + lane;
      int i3 = wb + 3 * 64 + lane;
      int i4 = wb + 4 * 64 + lane;
      n0 = (i0 < nf4) ? x4[i0] : zz;
      n1 = (i1 < nf4) ? x4[i1] : zz;
      n2 = (i2 < nf4) ? x4[i2] : zz;
      n3 = (i3 < nf4) ? x4[i3] : zz;
      n4 = (i4 < nf4) ? x4[i4] : zz;
    }

    // transposed read of current tile: thread gets its 2 contiguous rows
    float4 q0 = wl[lane * 5 + 0];
    float4 q1 = wl[lane * 5 + 1];
    float4 q2 = wl[lane * 5 + 2];
    float4 q3 = wl[lane * 5 + 3];
    float4 q4 = wl[lane * 5 + 4];
    float v[20] = {q0.x, q0.y, q0.z, q0.w, q1.x, q1.y, q1.z, q1.w,
                   q2.x, q2.y, q2.z, q2.w, q3.x, q3.y, q3.z, q3.w,
                   q4.x, q4.y, q4.z, q4.w};
    int k = 0;
#pragma unroll
    for (int i = 0; i < 10; i++) {
#pragma unroll
      for (int j = 0; j <= i; j++) {
        acc[k] += v[i] * v[j] + v[10 + i] * v[10 + j];
        k++;
      }
    }

    // write next tile into LDS (after this wave's reads; DS ops are in-order
    // within a wave, so no barrier is needed)
    if (an) {
      wl[0 * 64 + lane] = n0;
      wl[1 * 64 + lane] = n1;
      wl[2 * 64 + lane] = n2;
      wl[3 * 64 + lane] = n3;
      wl[4 * 64 + lane] = n4;
    }
    t = tn;
    active = an;
  }

  __shared__ double sred[4][55];
#pragma unroll
  for (int k = 0; k < 55; k++) {
    double d = (double)acc[k];
#pragma unroll
    for (int off = 32; off > 0; off >>= 1) d += __shfl_down(d, off, 64);
    if (lane == 0) sred[wv][k] = d;
  }
  __syncthreads();
  // 64-replica atomic tail: 16 RMWs/address spread over 440 cache lines.
  if (threadIdx.x < 55) {
    double s = sred[0][threadIdx.x] + sred[1][threadIdx.x] +
               sred[2][threadIdx.x] + sred[3][threadIdx.x];
    atomicAdd(&g[threadIdx.x * NREP + (blockIdx.x & (NREP - 1))], s);
  }
}

// ------------------------- LAPACK helpers (fp32) ---------------------------

__device__ __forceinline__ float sf_sign(float a, float b) {
  return (b >= 0.0f) ? fabsf(a) : -fabsf(a);
}

__device__ __forceinline__ float slapy2(float x, float y) {
  float xa = fabsf(x), ya = fabsf(y);
  float w = fmaxf(xa, ya), z = fminf(xa, ya);
  if (z == 0.0f) return w;
  float q = z / w;
  return w * sqrtf(1.0f + q * q);
}

// LAPACK >= 3.10 slartg: c = |f|/d >= 0, r = sign(f)*d, s = g/r
__device__ __forceinline__ void slartg(float f, float g, float* c, float* s, float* r) {
  if (g == 0.0f) {
    *c = 1.0f; *s = 0.0f; *r = f;
  } else if (f == 0.0f) {
    *c = 0.0f; *s = sf_sign(1.0f, g); *r = fabsf(g);
  } else {
    float d = sqrtf(f * f + g * g);
    *c = fabsf(f) / d;
    float rr = sf_sign(d, f);
    *s = g / rr;
    *r = rr;
  }
}

__device__ __forceinline__ void slaev2(float a, float b, float c,
                                       float* rt1, float* rt2, float* cs1, float* sn1) {
  float sm = a + c;
  float df = a - c;
  float adf = fabsf(df);
  float tb = b + b;
  float ab = fabsf(tb);
  float acmx, acmn;
  if (fabsf(a) > fabsf(c)) { acmx = a; acmn = c; } else { acmx = c; acmn = a; }
  float rt;
  if (adf > ab)      { float t = ab / adf; rt = adf * sqrtf(1.0f + t * t); }
  else if (adf < ab) { float t = adf / ab; rt = ab * sqrtf(1.0f + t * t); }
  else               { rt = ab * sqrtf(2.0f); }
  int sgn1;
  if (sm < 0.0f) {
    *rt1 = 0.5f * (sm - rt); sgn1 = -1;
    *rt2 = (acmx / *rt1) * acmn - (b / *rt1) * b;
  } else if (sm > 0.0f) {
    *rt1 = 0.5f * (sm + rt); sgn1 = 1;
    *rt2 = (acmx / *rt1) * acmn - (b / *rt1) * b;
  } else {
    *rt1 = 0.5f * rt; *rt2 = -0.5f * rt; sgn1 = 1;
  }
  int sgn2;
  float cs;
  if (df >= 0.0f) { cs = df + rt; sgn2 = 1; } else { cs = df - rt; sgn2 = -1; }
  float acs = fabsf(cs);
  if (acs > ab) {
    float ct = -tb / cs;
    *sn1 = 1.0f / sqrtf(1.0f + ct * ct);
    *cs1 = ct * (*sn1);
  } else {
    if (ab == 0.0f) { *cs1 = 1.0f; *sn1 = 0.0f; }
    else {
      float tn = -cs / tb;
      *cs1 = 1.0f / sqrtf(1.0f + tn * tn);
      *sn1 = tn * (*cs1);
    }
  }
  if (sgn1 == sgn2) { float tn = *cs1; *cs1 = -(*sn1); *sn1 = tn; }
}

// 10-way register select / masked write (runtime idx0, 0-based); branch-free.
// Used ONLY outside hot loops (once-per-sweep spots, 2x2 blocks, sort).
__device__ __forceinline__ float sel10(const float* a, int idx0) {
  float v = 0.0f;
#pragma unroll
  for (int k = 0; k < 10; k++) v = (k == idx0) ? a[k] : v;
  return v;
}
__device__ __forceinline__ void put10(float* a, int idx0, float v) {
#pragma unroll
  for (int k = 0; k < 10; k++) a[k] = (k == idx0) ? v : a[k];
}

// static 1-based access macros (indices must be compile-time constants)
#define A_(r, c) Am[((r)-1) * 10 + ((c)-1)]
#define Z_(r, c) Zm[((r)-1) * 10 + ((c)-1)]
#define D_(i) dv[(i)-1]
#define E_(i) ev[(i)-1]
#define TAUV(i) tauv[(i)-1]
#define WV(i) wvv[(i)-1]

__global__ __launch_bounds__(64, 1) void eig_mlp_kernel(
    const double* __restrict__ g,
    const float* __restrict__ W1,
    const float* __restrict__ b1,
    const float* __restrict__ W2,
    const float* __restrict__ b2,
    float* __restrict__ out) {
  if (blockIdx.x != 0) return;
  const int lane = threadIdx.x;
  const int n = 10;
  float Am[100], Zm[100];
  float dv[10], ev[10], tauv[10], wvv[10], csv[10], snv[10];

  // -------- reduce 64 replicas per component (1 coalesced load + tree) ----
  __shared__ double gsum[55];
#pragma unroll
  for (int k = 0; k < 55; k++) {
    double s = g[k * NREP + lane];
#pragma unroll
    for (int off = 32; off > 0; off >>= 1) s += __shfl_down(s, off, 64);
    if (lane == 0) gsum[k] = s;
  }
  __syncthreads();

  // load gram, round to fp32 — uniform on all lanes
  {
    int k = 0;
#pragma unroll
    for (int i = 0; i < 10; i++)
#pragma unroll
      for (int j = 0; j <= i; j++) {
        float f = (float)gsum[k];
        Am[i * 10 + j] = f;
        Am[j * 10 + i] = f;
        k++;
      }
  }

  // -------- ssytd2 (UPLO='L'), static, register-resident, uniform --------
#pragma unroll
  for (int i = 1; i <= n - 1; i++) {
    const int nmi = n - i;
    float alpha = A_(i + 1, i);
    float taui = 0.0f;
    if (nmi > 1) {
      float ss = 0.0f;
#pragma unroll
      for (int r = i + 2; r <= n; r++) { float t = A_(r, i); ss += t * t; }
      float xnorm = sqrtf(ss);
      if (xnorm != 0.0f) {
        float beta = -sf_sign(slapy2(alpha, xnorm), alpha);
        taui = (beta - alpha) / beta;
        float sc = 1.0f / (alpha - beta);
#pragma unroll
        for (int r = i + 2; r <= n; r++) A_(r, i) *= sc;
        alpha = beta;
      }
    }
    E_(i) = alpha;
    A_(i + 1, i) = alpha;
    if (taui != 0.0f) {
      A_(i + 1, i) = 1.0f;
#pragma unroll
      for (int r = i + 1; r <= n; r++) {
        float s = 0.0f;
#pragma unroll
        for (int c = i + 1; c <= n; c++) {
          float arc = (r >= c) ? A_(r, c) : A_(c, r);
          s += arc * A_(c, i);
        }
        WV(r) = taui * s;
      }
      float dot = 0.0f;
#pragma unroll
      for (int r = i + 1; r <= n; r++) dot += WV(r) * A_(r, i);
      float al2 = -0.5f * taui * dot;
#pragma unroll
      for (int r = i + 1; r <= n; r++) WV(r) += al2 * A_(r, i);
#pragma unroll
      for (int c = i + 1; c <= n; c++)
#pragma unroll
        for (int r = c; r <= n; r++)
          A_(r, c) -= A_(r, i) * WV(c) + WV(r) * A_(c, i);
      A_(i + 1, i) = E_(i);
    }
    D_(i) = A_(i, i);
    TAUV(i) = taui;
  }
  D_(n) = A_(n, n);

  // -------- form Q0 = H(1)...H(n-1), static, uniform --------
#pragma unroll
  for (int r = 1; r <= n; r++)
#pragma unroll
    for (int c = 1; c <= n; c++) Z_(r, c) = (r == c) ? 1.0f : 0.0f;
#pragma unroll
  for (int i = n - 1; i >= 1; i--) {
    float taui = TAUV(i);
    if (taui != 0.0f) {
#pragma unroll
      for (int c = 1; c <= n; c++) {
        float t = Z_(i + 1, c);
#pragma unroll
        for (int r = i + 2; r <= n; r++) t += A_(r, i) * Z_(r, c);
        t *= taui;
        Z_(i + 1, c) -= t;
#pragma unroll
        for (int r = i + 2; r <= n; r++) Z_(r, c) -= A_(r, i) * t;
      }
    }
  }

  // -------- distribute Z rows: lane r holds row r as z[0..9] --------
  const int r_own = (lane < 10) ? lane : 0;
  float z[10];
#pragma unroll
  for (int k = 0; k < 10; k++) {
    float v = Zm[0 * 10 + k];
#pragma unroll
    for (int rr = 1; rr < 10; rr++) v = (r_own == rr) ? Zm[rr * 10 + k] : v;
    z[k] = v;
  }

  // -------- ssteqr ('V'); sweeps statically unrolled w/ range guards ------
  const float eps = 5.9604644775390625e-08f;      // 2^-24
  const float eps2 = eps * eps;
  const float safmin = 1.17549435082228751e-38f;  // 2^-126
  const int nmaxit = n * 30;
  int jtot = 0;
  int l1 = 1;
  int guard = 0;

  while (l1 <= n && guard++ < 2000) {
    if (l1 > 1) put10(ev, l1 - 2, 0.0f);  // E_(l1-1) = 0
    int m = n;
    {
      bool found = false;
#pragma unroll
      for (int k = 1; k <= n - 1; k++) {
        if (!found && k >= l1) {
          float tst = fabsf(ev[k - 1]);
          if (tst == 0.0f) {
            m = k; found = true;
          } else if (tst <= (sqrtf(fabsf(dv[k - 1])) * sqrtf(fabsf(dv[k]))) * eps) {
            ev[k - 1] = 0.0f;
            m = k; found = true;
          }
        }
      }
    }
    int l = l1, lsv = l, lend = m, lendsv = m;
    l1 = m + 1;
    if (lend == l) continue;
    if (fabsf(sel10(dv, lend - 1)) < fabsf(sel10(dv, l - 1))) { lend = lsv; l = lendsv; }

    if (lend > l) {
      // ---------------- QL iteration ----------------
      for (;;) {
        if (guard++ > 4000) break;
        int m2 = lend;
        if (l != lend) {
          bool fnd = false;
#pragma unroll
          for (int k = 1; k <= n - 1; k++) {
            if (!fnd && k >= l && k <= lend - 1) {
              float e = ev[k - 1];
              if (e * e <= (eps2 * fabsf(dv[k - 1])) * fabsf(dv[k]) + safmin) {
                m2 = k; fnd = true;
              }
            }
          }
        }
        if (m2 < lend) put10(ev, m2 - 1, 0.0f);
        float p = sel10(dv, l - 1);
        if (m2 == l) {  // eigenvalue found
          put10(dv, l - 1, p);
          l = l + 1;
          if (l <= lend) continue;
          break;
        }
        if (m2 == l + 1) {  // 2x2 block; 0-based cols (l, l-1)
          float rt1, rt2, c2, s2;
          slaev2(sel10(dv, l - 1), sel10(ev, l - 1), sel10(dv, l), &rt1, &rt2, &c2, &s2);
          float a = sel10(z, l);
          float b = sel10(z, l - 1);
          put10(z, l, c2 * a - s2 * b);
          put10(z, l - 1, s2 * a + c2 * b);
          put10(dv, l - 1, rt1);
          put10(dv, l, rt2);
          put10(ev, l - 1, 0.0f);
          l = l + 2;
          if (l <= lend) continue;
          break;
        }
        if (jtot == nmaxit) break;
        jtot++;
        float El = sel10(ev, l - 1);
        float gg = (sel10(dv, l) - p) / (2.0f * El);
        float rr = slapy2(gg, 1.0f);
        gg = sel10(dv, m2 - 1) - p + (El / (gg + sf_sign(rr, gg)));
        float s = 1.0f, c = 1.0f;
        p = 0.0f;
        // rotation recurrence, static descending unroll w/ scalar guards
#pragma unroll
        for (int i = n - 1; i >= 1; i--) {
          if (i <= m2 - 1 && i >= l) {
            float e = ev[i - 1];
            float f = s * e, b = c * e;
            slartg(gg, f, &c, &s, &rr);
            if (i != m2 - 1) ev[i] = rr;  // E_(i+1), static
            gg = dv[i] - p;               // D_(i+1)
            rr = (dv[i - 1] - gg) * s + 2.0f * c * b;
            p = s * rr;
            dv[i] = gg + p;
            gg = c * rr - b;
            csv[i - 1] = c;
            snv[i - 1] = -s;
          }
        }
        // apply rotations (slasr 'B'): descending j, 0-based cols (j, j-1)
        {
          float a = sel10(z, m2 - 1);  // carried updated value of col j
#pragma unroll
          for (int j = n - 1; j >= 1; j--) {
            if (j <= m2 - 1 && j >= l) {
              float cj = csv[j - 1], sj = snv[j - 1];  // static
              float b = z[j - 1];                      // untouched original
              z[j] = cj * a - sj * b;                  // final col j
              a = sj * a + cj * b;                     // new col j-1, carried
            }
          }
          put10(z, l - 1, a);
        }
        put10(dv, l - 1, sel10(dv, l - 1) - p);
        put10(ev, l - 1, gg);
      }
    } else {
      // ---------------- QR iteration ----------------
      for (;;) {
        if (guard++ > 4000) break;
        int m2 = lend;
        if (l != lend) {
          bool fnd = false;
#pragma unroll
          for (int k = n; k >= 2; k--) {
            if (!fnd && k <= l && k >= lend + 1) {
              float e = ev[k - 2];
              if (e * e <= (eps2 * fabsf(dv[k - 1])) * fabsf(dv[k - 2]) + safmin) {
                m2 = k; fnd = true;
              }
            }
          }
        }
        if (m2 > lend) put10(ev, m2 - 2, 0.0f);  // E_(m2-1) = 0
        float p = sel10(dv, l - 1);
        if (m2 == l) {  // eigenvalue found
          put10(dv, l - 1, p);
          l = l - 1;
          if (l >= lend) continue;
          break;
        }
        if (m2 == l - 1) {  // 2x2 block; 0-based cols (l-1, l-2)
          float rt1, rt2, c2, s2;
          slaev2(sel10(dv, l - 2), sel10(ev, l - 2), sel10(dv, l - 1), &rt1, &rt2, &c2, &s2);
          float a = sel10(z, l - 1);
          float b = sel10(z, l - 2);
          put10(z, l - 1, c2 * a - s2 * b);
          put10(z, l - 2, s2 * a + c2 * b);
          put10(dv, l - 2, rt1);
          put10(dv, l - 1, rt2);
          put10(ev, l - 2, 0.0f);
          l = l - 2;
          if (l >= lend) continue;
          break;
        }
        if (jtot == nmaxit) break;
        jtot++;
        float El1 = sel10(ev, l - 2);  // E_(l-1)
        float gg = (sel10(dv, l - 2) - p) / (2.0f * El1);
        float rr = slapy2(gg, 1.0f);
        gg = sel10(dv, m2 - 1) - p + (El1 / (gg + sf_sign(rr, gg)));
        float s = 1.0f, c = 1.0f;
        p = 0.0f;
        // rotation recurrence, static ascending unroll w/ scalar guards
#pragma unroll
        for (int i = 1; i <= n - 1; i++) {
          if (i >= m2 && i <= l - 1) {
            float e = ev[i - 1];
            float f = s * e, b = c * e;
            slartg(gg, f, &c, &s, &rr);
            if (i >= 2) {
              if (i != m2) ev[i - 2] = rr;  // E_(i-1), static
            }
            gg = dv[i - 1] - p;  // D_(i)
            rr = (dv[i] - gg) * s + 2.0f * c * b;
            p = s * rr;
            dv[i - 1] = gg + p;
            gg = c * rr - b;
            csv[i - 1] = c;
            snv[i - 1] = s;
          }
        }
        // apply rotations (slasr 'F'): ascending j, 0-based cols (j, j-1)
        {
          float carry = sel10(z, m2 - 1);  // current value of col j-1
#pragma unroll
          for (int j = 1; j <= n - 1; j++) {
            if (j >= m2 && j <= l - 1) {
              float cj = csv[j - 1], sj = snv[j - 1];  // static
              float t = z[j];                          // untouched original
              z[j - 1] = sj * t + cj * carry;          // final col j-1
              carry = cj * t - sj * carry;             // new col j, carried
            }
          }
          put10(z, l - 1, carry);
        }
        put10(dv, l - 1, sel10(dv, l - 1) - p);
        put10(ev, l - 2, gg);  // E_(l-1)
      }
    }
  }

  // -------- selection sort ascending (as in ssteqr), uniform --------
  for (int ii = 2; ii <= n; ii++) {
    int i = ii - 1;
    int k = i;
    float p = sel10(dv, i - 1);
    for (int j = ii; j <= n; j++) {
      float dj = sel10(dv, j - 1);
      if (dj < p) { k = j; p = dj; }
    }
    if (k != i) {
      float di = sel10(dv, i - 1);
      put10(dv, k - 1, di);
      put10(dv, i - 1, p);
      float a = sel10(z, i - 1), b = sel10(z, k - 1);
      put10(z, i - 1, b);
      put10(z, k - 1, a);
    }
  }

  // -------- MLP per lane (lane r computes output row r) --------
  if (lane < 10) {
    double o = (double)b2[0];
#pragma unroll
    for (int h = 0; h < 16; h++) {
      double sgm = (double)b1[h];
#pragma unroll
      for (int k = 0; k < 10; k++) sgm += (double)z[k] * (double)W1[h * 10 + k];
      if (sgm > 0.0) o += sgm * (double)W2[h];
    }
    double sig = 1.0 / (1.0 + exp(-o));
    out[lane] = (float)(0.5 * (sig + 1.0));
  }
}

extern "C" void kernel_launch(void* const* d_in, const int* in_sizes, int n_in,
                              void* d_out, int out_size, void* d_ws, size_t ws_size,
                              hipStream_t stream) {
  const float* x  = (const float*)d_in[0];
  const float* W1 = (const float*)d_in[1];
  const float* b1 = (const float*)d_in[2];
  const float* W2 = (const float*)d_in[3];
  const float* b2 = (const float*)d_in[4];
  double* g = (double*)d_ws;
  float* out = (float*)d_out;

  int nf4 = in_sizes[0] / 4;  // 10M float4

  zero_ws_kernel<<<14, 256, 0, stream>>>(g);
  gram_kernel<<<GRID2, BLK2, 0, stream>>>((const float4*)x, g, nf4);
  eig_mlp_kernel<<<1, 64, 0, stream>>>(g, W1, b1, W2, b2, out);
}

// Round 6
// 332.388 us; speedup vs baseline: 1.0989x; 1.0914x over previous
//
#include <hip/hip_runtime.h>
#include <math.h>

// ---------------------------------------------------------------------------
// gram = x^T x (N=4M, D=10, fp64-accurate reduction) -> fp32 -> LAPACK-
// faithful fp32 ssyevd path (ssytd2 'L' + ssteqr, LAPACK>=3.10 slartg) -> MLP.
// Round 10 (eig register pressure): pressure-free replica reduction.
// [Round 11 = identical resubmit: round-10 bench was an infra failure
//  ("MI355X container failed twice") — kernel never executed.]
//  * Round 9 counters: eig VGPR_Count=80 with ~260 live floats (Am/Zm/...)
//    -> arrays spilled to SCRATCH; FETCH_SIZE 68.75KB == 260 f32 x 64 lanes
//    (the scratch footprint). Single serial wave x ~200cy L2 scratch trips
//    = the ~100us main body. Rounds 0-7 (total arithmetic) imply the SAME
//    body ran ~55us -> the round-8/9 prologue (55 unrolled 6-deep fp64
//    shuffle webs + LDS) perturbed regalloc into the spill regime.
//  * Round 10: replicas stored r-major g[r*55+k]; gram tail atomicAdds 55
//    consecutive doubles per replica (same 16-RMW/address contention).
//    eig prologue: lane k serially sums the 64 replicas of component k
//    (64 unrolled independent 8B loads, no shuffles, no cross-lane webs,
//    ~10 VGPR pressure), one ds_write, barrier, uniform reads. fp64
//    reassociation proven safe (absmax 0.0 across 3 summation orders).
//  * gram load loop (round 7) and the entire eig main body are untouched.
// ---------------------------------------------------------------------------

#define BLK2 256
#define GRID2 1024
#define NREP 64                      // partial-sum replicas (16 RMWs/address)
#define WTILE_F4 320                 // per-wave tile: 5 steps x 64 lanes
#define TILE_F4 (BLK2 * 5)           // 1280 float4 = 512 rows per block tile

__global__ void zero_ws_kernel(double* __restrict__ g) {
  int t = blockIdx.x * 256 + threadIdx.x;
  if (t < 55 * NREP) g[t] = 0.0;
}

__global__ __launch_bounds__(BLK2) void gram_kernel(const float4* __restrict__ x4,
                                                    double* __restrict__ g,
                                                    int nf4) {
  __shared__ float4 lds[4][WTILE_F4];  // 4 waves x 5KB, wave-private slices
  float acc[55];
#pragma unroll
  for (int k = 0; k < 55; k++) acc[k] = 0.0f;

  const int tid = threadIdx.x;
  const int lane = tid & 63;
  const int wv = tid >> 6;
  float4* const wl = lds[wv];
  const int ntiles = (nf4 + TILE_F4 - 1) / TILE_F4;
  const float4 zz = make_float4(0.f, 0.f, 0.f, 0.f);

  int t = (int)blockIdx.x;
  bool active = (t < ntiles);

  // stage tile t into this wave's LDS slice (coalesced, guarded)
  if (active) {
    const int wb = t * TILE_F4 + wv * WTILE_F4;
#pragma unroll
    for (int s = 0; s < 5; s++) {
      int i = wb + s * 64 + lane;
      wl[s * 64 + lane] = (i < nf4) ? x4[i] : zz;
    }
  }

  while (active) {
    // issue next tile's coalesced loads into registers (overlaps compute)
    const int tn = t + GRID2;
    const bool an = (tn < ntiles);
    float4 n0 = zz, n1 = zz, n2 = zz, n3 = zz, n4 = zz;
    if (an) {
      const int wb = tn * TILE_F4 + wv * WTILE_F4;
      int i0 = wb + 0 * 64 + lane;
      int i1 = wb + 1 * 64 + lane;
      int i2 = wb + 2 * 64 + lane;
      int i3 = wb + 3 * 64 + lane;
      int i4 = wb + 4 * 64 + lane;
      n0 = (i0 < nf4) ? x4[i0] : zz;
      n1 = (i1 < nf4) ? x4[i1] : zz;
      n2 = (i2 < nf4) ? x4[i2] : zz;
      n3 = (i3 < nf4) ? x4[i3] : zz;
      n4 = (i4 < nf4) ? x4[i4] : zz;
    }

    // transposed read of current tile: thread gets its 2 contiguous rows
    float4 q0 = wl[lane * 5 + 0];
    float4 q1 = wl[lane * 5 + 1];
    float4 q2 = wl[lane * 5 + 2];
    float4 q3 = wl[lane * 5 + 3];
    float4 q4 = wl[lane * 5 + 4];
    float v[20] = {q0.x, q0.y, q0.z, q0.w, q1.x, q1.y, q1.z, q1.w,
                   q2.x, q2.y, q2.z, q2.w, q3.x, q3.y, q3.z, q3.w,
                   q4.x, q4.y, q4.z, q4.w};
    int k = 0;
#pragma unroll
    for (int i = 0; i < 10; i++) {
#pragma unroll
      for (int j = 0; j <= i; j++) {
        acc[k] += v[i] * v[j] + v[10 + i] * v[10 + j];
        k++;
      }
    }

    // write next tile into LDS (after this wave's reads; DS ops are in-order
    // within a wave, so no barrier is needed)
    if (an) {
      wl[0 * 64 + lane] = n0;
      wl[1 * 64 + lane] = n1;
      wl[2 * 64 + lane] = n2;
      wl[3 * 64 + lane] = n3;
      wl[4 * 64 + lane] = n4;
    }
    t = tn;
    active = an;
  }

  __shared__ double sred[4][55];
#pragma unroll
  for (int k = 0; k < 55; k++) {
    double d = (double)acc[k];
#pragma unroll
    for (int off = 32; off > 0; off >>= 1) d += __shfl_down(d, off, 64);
    if (lane == 0) sred[wv][k] = d;
  }
  __syncthreads();
  // 64-replica atomic tail, r-major: replica r = blk&63 owns g[r*55..r*55+54]
  // (55 consecutive doubles -> 7 lines/replica; 16 RMWs per address).
  if (threadIdx.x < 55) {
    double s = sred[0][threadIdx.x] + sred[1][threadIdx.x] +
               sred[2][threadIdx.x] + sred[3][threadIdx.x];
    atomicAdd(&g[(blockIdx.x & (NREP - 1)) * 55 + threadIdx.x], s);
  }
}

// ------------------------- LAPACK helpers (fp32) ---------------------------

__device__ __forceinline__ float sf_sign(float a, float b) {
  return (b >= 0.0f) ? fabsf(a) : -fabsf(a);
}

__device__ __forceinline__ float slapy2(float x, float y) {
  float xa = fabsf(x), ya = fabsf(y);
  float w = fmaxf(xa, ya), z = fminf(xa, ya);
  if (z == 0.0f) return w;
  float q = z / w;
  return w * sqrtf(1.0f + q * q);
}

// LAPACK >= 3.10 slartg: c = |f|/d >= 0, r = sign(f)*d, s = g/r
__device__ __forceinline__ void slartg(float f, float g, float* c, float* s, float* r) {
  if (g == 0.0f) {
    *c = 1.0f; *s = 0.0f; *r = f;
  } else if (f == 0.0f) {
    *c = 0.0f; *s = sf_sign(1.0f, g); *r = fabsf(g);
  } else {
    float d = sqrtf(f * f + g * g);
    *c = fabsf(f) / d;
    float rr = sf_sign(d, f);
    *s = g / rr;
    *r = rr;
  }
}

__device__ __forceinline__ void slaev2(float a, float b, float c,
                                       float* rt1, float* rt2, float* cs1, float* sn1) {
  float sm = a + c;
  float df = a - c;
  float adf = fabsf(df);
  float tb = b + b;
  float ab = fabsf(tb);
  float acmx, acmn;
  if (fabsf(a) > fabsf(c)) { acmx = a; acmn = c; } else { acmx = c; acmn = a; }
  float rt;
  if (adf > ab)      { float t = ab / adf; rt = adf * sqrtf(1.0f + t * t); }
  else if (adf < ab) { float t = adf / ab; rt = ab * sqrtf(1.0f + t * t); }
  else               { rt = ab * sqrtf(2.0f); }
  int sgn1;
  if (sm < 0.0f) {
    *rt1 = 0.5f * (sm - rt); sgn1 = -1;
    *rt2 = (acmx / *rt1) * acmn - (b / *rt1) * b;
  } else if (sm > 0.0f) {
    *rt1 = 0.5f * (sm + rt); sgn1 = 1;
    *rt2 = (acmx / *rt1) * acmn - (b / *rt1) * b;
  } else {
    *rt1 = 0.5f * rt; *rt2 = -0.5f * rt; sgn1 = 1;
  }
  int sgn2;
  float cs;
  if (df >= 0.0f) { cs = df + rt; sgn2 = 1; } else { cs = df - rt; sgn2 = -1; }
  float acs = fabsf(cs);
  if (acs > ab) {
    float ct = -tb / cs;
    *sn1 = 1.0f / sqrtf(1.0f + ct * ct);
    *cs1 = ct * (*sn1);
  } else {
    if (ab == 0.0f) { *cs1 = 1.0f; *sn1 = 0.0f; }
    else {
      float tn = -cs / tb;
      *cs1 = 1.0f / sqrtf(1.0f + tn * tn);
      *sn1 = tn * (*cs1);
    }
  }
  if (sgn1 == sgn2) { float tn = *cs1; *cs1 = -(*sn1); *sn1 = tn; }
}

// 10-way register select / masked write (runtime idx0, 0-based); branch-free.
// Used ONLY outside hot loops (once-per-sweep spots, 2x2 blocks, sort).
__device__ __forceinline__ float sel10(const float* a, int idx0) {
  float v = 0.0f;
#pragma unroll
  for (int k = 0; k < 10; k++) v = (k == idx0) ? a[k] : v;
  return v;
}
__device__ __forceinline__ void put10(float* a, int idx0, float v) {
#pragma unroll
  for (int k = 0; k < 10; k++) a[k] = (k == idx0) ? v : a[k];
}

// static 1-based access macros (indices must be compile-time constants)
#define A_(r, c) Am[((r)-1) * 10 + ((c)-1)]
#define Z_(r, c) Zm[((r)-1) * 10 + ((c)-1)]
#define D_(i) dv[(i)-1]
#define E_(i) ev[(i)-1]
#define TAUV(i) tauv[(i)-1]
#define WV(i) wvv[(i)-1]

__global__ __launch_bounds__(64, 1) void eig_mlp_kernel(
    const double* __restrict__ g,
    const float* __restrict__ W1,
    const float* __restrict__ b1,
    const float* __restrict__ W2,
    const float* __restrict__ b2,
    float* __restrict__ out) {
  if (blockIdx.x != 0) return;
  const int lane = threadIdx.x;
  const int n = 10;
  float Am[100], Zm[100];
  float dv[10], ev[10], tauv[10], wvv[10], csv[10], snv[10];

  // -------- reduce 64 replicas: lane k serially sums component k ----------
  // (64 independent 8B loads per lane, no shuffles/webs -> ~10 VGPR pressure)
  __shared__ double gsum[55];
  if (lane < 55) {
    double s = 0.0;
#pragma unroll
    for (int j = 0; j < NREP; j++) s += g[j * 55 + lane];
    gsum[lane] = s;
  }
  __syncthreads();

  // load gram, round to fp32 — uniform on all lanes
  {
    int k = 0;
#pragma unroll
    for (int i = 0; i < 10; i++)
#pragma unroll
      for (int j = 0; j <= i; j++) {
        float f = (float)gsum[k];
        Am[i * 10 + j] = f;
        Am[j * 10 + i] = f;
        k++;
      }
  }

  // -------- ssytd2 (UPLO='L'), static, register-resident, uniform --------
#pragma unroll
  for (int i = 1; i <= n - 1; i++) {
    const int nmi = n - i;
    float alpha = A_(i + 1, i);
    float taui = 0.0f;
    if (nmi > 1) {
      float ss = 0.0f;
#pragma unroll
      for (int r = i + 2; r <= n; r++) { float t = A_(r, i); ss += t * t; }
      float xnorm = sqrtf(ss);
      if (xnorm != 0.0f) {
        float beta = -sf_sign(slapy2(alpha, xnorm), alpha);
        taui = (beta - alpha) / beta;
        float sc = 1.0f / (alpha - beta);
#pragma unroll
        for (int r = i + 2; r <= n; r++) A_(r, i) *= sc;
        alpha = beta;
      }
    }
    E_(i) = alpha;
    A_(i + 1, i) = alpha;
    if (taui != 0.0f) {
      A_(i + 1, i) = 1.0f;
#pragma unroll
      for (int r = i + 1; r <= n; r++) {
        float s = 0.0f;
#pragma unroll
        for (int c = i + 1; c <= n; c++) {
          float arc = (r >= c) ? A_(r, c) : A_(c, r);
          s += arc * A_(c, i);
        }
        WV(r) = taui * s;
      }
      float dot = 0.0f;
#pragma unroll
      for (int r = i + 1; r <= n; r++) dot += WV(r) * A_(r, i);
      float al2 = -0.5f * taui * dot;
#pragma unroll
      for (int r = i + 1; r <= n; r++) WV(r) += al2 * A_(r, i);
#pragma unroll
      for (int c = i + 1; c <= n; c++)
#pragma unroll
        for (int r = c; r <= n; r++)
          A_(r, c) -= A_(r, i) * WV(c) + WV(r) * A_(c, i);
      A_(i + 1, i) = E_(i);
    }
    D_(i) = A_(i, i);
    TAUV(i) = taui;
  }
  D_(n) = A_(n, n);

  // -------- form Q0 = H(1)...H(n-1), static, uniform --------
#pragma unroll
  for (int r = 1; r <= n; r++)
#pragma unroll
    for (int c = 1; c <= n; c++) Z_(r, c) = (r == c) ? 1.0f : 0.0f;
#pragma unroll
  for (int i = n - 1; i >= 1; i--) {
    float taui = TAUV(i);
    if (taui != 0.0f) {
#pragma unroll
      for (int c = 1; c <= n; c++) {
        float t = Z_(i + 1, c);
#pragma unroll
        for (int r = i + 2; r <= n; r++) t += A_(r, i) * Z_(r, c);
        t *= taui;
        Z_(i + 1, c) -= t;
#pragma unroll
        for (int r = i + 2; r <= n; r++) Z_(r, c) -= A_(r, i) * t;
      }
    }
  }

  // -------- distribute Z rows: lane r holds row r as z[0..9] --------
  const int r_own = (lane < 10) ? lane : 0;
  float z[10];
#pragma unroll
  for (int k = 0; k < 10; k++) {
    float v = Zm[0 * 10 + k];
#pragma unroll
    for (int rr = 1; rr < 10; rr++) v = (r_own == rr) ? Zm[rr * 10 + k] : v;
    z[k] = v;
  }

  // -------- ssteqr ('V'); sweeps statically unrolled w/ range guards ------
  const float eps = 5.9604644775390625e-08f;      // 2^-24
  const float eps2 = eps * eps;
  const float safmin = 1.17549435082228751e-38f;  // 2^-126
  const int nmaxit = n * 30;
  int jtot = 0;
  int l1 = 1;
  int guard = 0;

  while (l1 <= n && guard++ < 2000) {
    if (l1 > 1) put10(ev, l1 - 2, 0.0f);  // E_(l1-1) = 0
    int m = n;
    {
      bool found = false;
#pragma unroll
      for (int k = 1; k <= n - 1; k++) {
        if (!found && k >= l1) {
          float tst = fabsf(ev[k - 1]);
          if (tst == 0.0f) {
            m = k; found = true;
          } else if (tst <= (sqrtf(fabsf(dv[k - 1])) * sqrtf(fabsf(dv[k]))) * eps) {
            ev[k - 1] = 0.0f;
            m = k; found = true;
          }
        }
      }
    }
    int l = l1, lsv = l, lend = m, lendsv = m;
    l1 = m + 1;
    if (lend == l) continue;
    if (fabsf(sel10(dv, lend - 1)) < fabsf(sel10(dv, l - 1))) { lend = lsv; l = lendsv; }

    if (lend > l) {
      // ---------------- QL iteration ----------------
      for (;;) {
        if (guard++ > 4000) break;
        int m2 = lend;
        if (l != lend) {
          bool fnd = false;
#pragma unroll
          for (int k = 1; k <= n - 1; k++) {
            if (!fnd && k >= l && k <= lend - 1) {
              float e = ev[k - 1];
              if (e * e <= (eps2 * fabsf(dv[k - 1])) * fabsf(dv[k]) + safmin) {
                m2 = k; fnd = true;
              }
            }
          }
        }
        if (m2 < lend) put10(ev, m2 - 1, 0.0f);
        float p = sel10(dv, l - 1);
        if (m2 == l) {  // eigenvalue found
          put10(dv, l - 1, p);
          l = l + 1;
          if (l <= lend) continue;
          break;
        }
        if (m2 == l + 1) {  // 2x2 block; 0-based cols (l, l-1)
          float rt1, rt2, c2, s2;
          slaev2(sel10(dv, l - 1), sel10(ev, l - 1), sel10(dv, l), &rt1, &rt2, &c2, &s2);
          float a = sel10(z, l);
          float b = sel10(z, l - 1);
          put10(z, l, c2 * a - s2 * b);
          put10(z, l - 1, s2 * a + c2 * b);
          put10(dv, l - 1, rt1);
          put10(dv, l, rt2);
          put10(ev, l - 1, 0.0f);
          l = l + 2;
          if (l <= lend) continue;
          break;
        }
        if (jtot == nmaxit) break;
        jtot++;
        float El = sel10(ev, l - 1);
        float gg = (sel10(dv, l) - p) / (2.0f * El);
        float rr = slapy2(gg, 1.0f);
        gg = sel10(dv, m2 - 1) - p + (El / (gg + sf_sign(rr, gg)));
        float s = 1.0f, c = 1.0f;
        p = 0.0f;
        // rotation recurrence, static descending unroll w/ scalar guards
#pragma unroll
        for (int i = n - 1; i >= 1; i--) {
          if (i <= m2 - 1 && i >= l) {
            float e = ev[i - 1];
            float f = s * e, b = c * e;
            slartg(gg, f, &c, &s, &rr);
            if (i != m2 - 1) ev[i] = rr;  // E_(i+1), static
            gg = dv[i] - p;               // D_(i+1)
            rr = (dv[i - 1] - gg) * s + 2.0f * c * b;
            p = s * rr;
            dv[i] = gg + p;
            gg = c * rr - b;
            csv[i - 1] = c;
            snv[i - 1] = -s;
          }
        }
        // apply rotations (slasr 'B'): descending j, 0-based cols (j, j-1)
        {
          float a = sel10(z, m2 - 1);  // carried updated value of col j
#pragma unroll
          for (int j = n - 1; j >= 1; j--) {
            if (j <= m2 - 1 && j >= l) {
              float cj = csv[j - 1], sj = snv[j - 1];  // static
              float b = z[j - 1];                      // untouched original
              z[j] = cj * a - sj * b;                  // final col j
              a = sj * a + cj * b;                     // new col j-1, carried
            }
          }
          put10(z, l - 1, a);
        }
        put10(dv, l - 1, sel10(dv, l - 1) - p);
        put10(ev, l - 1, gg);
      }
    } else {
      // ---------------- QR iteration ----------------
      for (;;) {
        if (guard++ > 4000) break;
        int m2 = lend;
        if (l != lend) {
          bool fnd = false;
#pragma unroll
          for (int k = n; k >= 2; k--) {
            if (!fnd && k <= l && k >= lend + 1) {
              float e = ev[k - 2];
              if (e * e <= (eps2 * fabsf(dv[k - 1])) * fabsf(dv[k - 2]) + safmin) {
                m2 = k; fnd = true;
              }
            }
          }
        }
        if (m2 > lend) put10(ev, m2 - 2, 0.0f);  // E_(m2-1) = 0
        float p = sel10(dv, l - 1);
        if (m2 == l) {  // eigenvalue found
          put10(dv, l - 1, p);
          l = l - 1;
          if (l >= lend) continue;
          break;
        }
        if (m2 == l - 1) {  // 2x2 block; 0-based cols (l-1, l-2)
          float rt1, rt2, c2, s2;
          slaev2(sel10(dv, l - 2), sel10(ev, l - 2), sel10(dv, l - 1), &rt1, &rt2, &c2, &s2);
          float a = sel10(z, l - 1);
          float b = sel10(z, l - 2);
          put10(z, l - 1, c2 * a - s2 * b);
          put10(z, l - 2, s2 * a + c2 * b);
          put10(dv, l - 2, rt1);
          put10(dv, l - 1, rt2);
          put10(ev, l - 2, 0.0f);
          l = l - 2;
          if (l >= lend) continue;
          break;
        }
        if (jtot == nmaxit) break;
        jtot++;
        float El1 = sel10(ev, l - 2);  // E_(l-1)
        float gg = (sel10(dv, l - 2) - p) / (2.0f * El1);
        float rr = slapy2(gg, 1.0f);
        gg = sel10(dv, m2 - 1) - p + (El1 / (gg + sf_sign(rr, gg)));
        float s = 1.0f, c = 1.0f;
        p = 0.0f;
        // rotation recurrence, static ascending unroll w/ scalar guards
#pragma unroll
        for (int i = 1; i <= n - 1; i++) {
          if (i >= m2 && i <= l - 1) {
            float e = ev[i - 1];
            float f = s * e, b = c * e;
            slartg(gg, f, &c, &s, &rr);
            if (i >= 2) {
              if (i != m2) ev[i - 2] = rr;  // E_(i-1), static
            }
            gg = dv[i - 1] - p;  // D_(i)
            rr = (dv[i] - gg) * s + 2.0f * c * b;
            p = s * rr;
            dv[i - 1] = gg + p;
            gg = c * rr - b;
            csv[i - 1] = c;
            snv[i - 1] = s;
          }
        }
        // apply rotations (slasr 'F'): ascending j, 0-based cols (j, j-1)
        {
          float carry = sel10(z, m2 - 1);  // current value of col j-1
#pragma unroll
          for (int j = 1; j <= n - 1; j++) {
            if (j >= m2 && j <= l - 1) {
              float cj = csv[j - 1], sj = snv[j - 1];  // static
              float t = z[j];                          // untouched original
              z[j - 1] = sj * t + cj * carry;          // final col j-1
              carry = cj * t - sj * carry;             // new col j, carried
            }
          }
          put10(z, l - 1, carry);
        }
        put10(dv, l - 1, sel10(dv, l - 1) - p);
        put10(ev, l - 2, gg);  // E_(l-1)
      }
    }
  }

  // -------- selection sort ascending (as in ssteqr), uniform --------
  for (int ii = 2; ii <= n; ii++) {
    int i = ii - 1;
    int k = i;
    float p = sel10(dv, i - 1);
    for (int j = ii; j <= n; j++) {
      float dj = sel10(dv, j - 1);
      if (dj < p) { k = j; p = dj; }
    }
    if (k != i) {
      float di = sel10(dv, i - 1);
      put10(dv, k - 1, di);
      put10(dv, i - 1, p);
      float a = sel10(z, i - 1), b = sel10(z, k - 1);
      put10(z, i - 1, b);
      put10(z, k - 1, a);
    }
  }

  // -------- MLP per lane (lane r computes output row r) --------
  if (lane < 10) {
    double o = (double)b2[0];
#pragma unroll
    for (int h = 0; h < 16; h++) {
      double sgm = (double)b1[h];
#pragma unroll
      for (int k = 0; k < 10; k++) sgm += (double)z[k] * (double)W1[h * 10 + k];
      if (sgm > 0.0) o += sgm * (double)W2[h];
    }
    double sig = 1.0 / (1.0 + exp(-o));
    out[lane] = (float)(0.5 * (sig + 1.0));
  }
}

extern "C" void kernel_launch(void* const* d_in, const int* in_sizes, int n_in,
                              void* d_out, int out_size, void* d_ws, size_t ws_size,
                              hipStream_t stream) {
  const float* x  = (const float*)d_in[0];
  const float* W1 = (const float*)d_in[1];
  const float* b1 = (const float*)d_in[2];
  const float* W2 = (const float*)d_in[3];
  const float* b2 = (const float*)d_in[4];
  double* g = (double*)d_ws;
  float* out = (float*)d_out;

  int nf4 = in_sizes[0] / 4;  // 10M float4

  zero_ws_kernel<<<14, 256, 0, stream>>>(g);
  gram_kernel<<<GRID2, BLK2, 0, stream>>>((const float4*)x, g, nf4);
  eig_mlp_kernel<<<1, 64, 0, stream>>>(g, W1, b1, W2, b2, out);
}